// Round 5
// baseline (114.135 us; speedup 1.0000x reference)
//
#include <hip/hip_runtime.h>
#include <math.h>

typedef _Float16 f16;
typedef f16   f16x4    __attribute__((ext_vector_type(4)));
typedef f16   f16x8    __attribute__((ext_vector_type(8)));
typedef float floatx2  __attribute__((ext_vector_type(2)));
typedef float floatx4  __attribute__((ext_vector_type(4)));
typedef float floatx16 __attribute__((ext_vector_type(16)));

#define LOG2E   1.44269504088896340736f
#define INV_2PI 0.15915494309189533577f

// Problem constants
#define B_SZ  2048
#define DIN   64
#define DOUT  64
#define NH    32

#define NIG   4                 // i-groups (occupancy: 8192 blocks)
#define IGW   (DIN / NIG)       // 16 i per block

// Images (built by prep_kernel), K=8-packed for mfma_32x32x8 (no zero half):
//  w1img f16 [i][o][lane(64)][j(4)]: A-frag, m=h=lane&31, k=(lane>>5)*4+j.
//        lane<32 -> k=0..3 -> W1[...,{x,s1,s2,s4}]; lane>=32 -> k=4..7 ->
//        {W1[4],W1[5],W1[6],B1} (bias via constant-1 feature). Scaled by -log2e.
//  fimg  f16 [i][btp(64)][lane(64)][j(4)]: B-frag, n=b=lane&31, k as above;
//        lane<32 -> {x,s1,s2,s4}; lane>=32 -> {c1,c2,c4,1}.
//  w2q   f32 [i][o][h(32)] = W2[i,o,h] * (-1/log2e)   (h-linear)
//  b2sum f32 [64]: column sums of B2.
#define W1IMG_ELEMS ((size_t)DIN * DOUT * 64 * 4)   // 1,048,576 f16 = 2 MB
#define FIMG_ELEMS  ((size_t)DIN * 64 * 64 * 4)     // 1,048,576 f16 = 2 MB
#define W2Q_ELEMS   ((size_t)DIN * DOUT * NH)       // 131,072 f32 = 512 KB

// ---- packed-f32 (VOP3P) helpers: force v_pk_* emission via inline asm ----
__device__ __forceinline__ floatx2 pk_add(floatx2 a, floatx2 b) {
    floatx2 d; asm("v_pk_add_f32 %0, %1, %2" : "=v"(d) : "v"(a), "v"(b)); return d;
}
__device__ __forceinline__ floatx2 pk_mul(floatx2 a, floatx2 b) {
    floatx2 d; asm("v_pk_mul_f32 %0, %1, %2" : "=v"(d) : "v"(a), "v"(b)); return d;
}
__device__ __forceinline__ floatx2 pk_fma(floatx2 a, floatx2 b, floatx2 c) {
    floatx2 d; asm("v_pk_fma_f32 %0, %1, %2, %3" : "=v"(d) : "v"(a), "v"(b), "v"(c)); return d;
}

// ---------------------------------------------------------------------------
// prep: bid [0,512) -> w1img, [512,1024) -> fimg, [1024,1152) -> w2q (float4
// scaled copy), [1152,1280) -> zero out[], 1280 -> b2sum.
// sin/cos via HW v_sin_f32/v_cos_f32 (input in revolutions; |x|/2pi < 0.8
// here, well inside the valid range; err ~2^-21 << f16 quantization).
// ---------------------------------------------------------------------------
__global__ __launch_bounds__(256) void prep_kernel(
        const float* __restrict__ W1, const float* __restrict__ B1,
        const float* __restrict__ W2, const float* __restrict__ B2,
        const float* __restrict__ x,
        f16* __restrict__ w1img, f16* __restrict__ fimg,
        float* __restrict__ w2q, float* __restrict__ b2sum,
        float* __restrict__ out) {
    const int bid = blockIdx.x, tid = threadIdx.x;
    if (bid < 512) {
        int u = bid * 256 + tid;             // [i][o][lane2] lane2 = lane pair
        int lane2 = u & 31, o = (u >> 5) & 63, i = u >> 11;
        int l0 = lane2 * 2;
        f16x8 v;
        if (lane2 < 16) {                    // rows l0,l0+1; k=0..3 -> w[0..3]
#pragma unroll
            for (int t = 0; t < 2; ++t) {
                const float* w = W1 + (size_t)((i * 64 + o) * 32 + l0 + t) * 7;
#pragma unroll
                for (int j = 0; j < 4; ++j) v[t * 4 + j] = (f16)(w[j] * (-LOG2E));
            }
        } else {                             // rows l0-32,l0-31; k=4..7 -> w[4..6],B1
#pragma unroll
            for (int t = 0; t < 2; ++t) {
                int m = l0 - 32 + t;
                const float* w = W1 + (size_t)((i * 64 + o) * 32 + m) * 7;
                v[t * 4 + 0] = (f16)(w[4] * (-LOG2E));
                v[t * 4 + 1] = (f16)(w[5] * (-LOG2E));
                v[t * 4 + 2] = (f16)(w[6] * (-LOG2E));
                v[t * 4 + 3] = (f16)(B1[(i * 64 + o) * 32 + m] * (-LOG2E));
            }
        }
        *(f16x8*)(w1img + (size_t)u * 8) = v;
    } else if (bid < 1024) {
        int u = (bid - 512) * 256 + tid;     // [i][btp][lane2]
        int lane2 = u & 31, btp = (u >> 5) & 63, i = u >> 11;
        int l0 = lane2 * 2;
        f16x8 v;
#pragma unroll
        for (int t = 0; t < 2; ++t) {
            int b = btp * 32 + ((l0 + t) & 31);
            float xv = x[b * 64 + i];
            float s1 = __builtin_amdgcn_sinf(xv * INV_2PI);
            float c1 = __builtin_amdgcn_cosf(xv * INV_2PI);
            float s2 = 2.0f * s1 * c1, c2 = 1.0f - 2.0f * s1 * s1;
            float s4 = 2.0f * s2 * c2, c4 = 1.0f - 2.0f * s2 * s2;
            if (lane2 < 16) { v[t*4+0] = (f16)xv; v[t*4+1] = (f16)s1;
                              v[t*4+2] = (f16)s2; v[t*4+3] = (f16)s4; }
            else            { v[t*4+0] = (f16)c1; v[t*4+1] = (f16)c2;
                              v[t*4+2] = (f16)c4; v[t*4+3] = (f16)1.0f; }
        }
        *(f16x8*)(fimg + (size_t)u * 8) = v;
    } else if (bid < 1152) {
        int t = (bid - 1024) * 256 + tid;    // < 32768 float4s
        floatx4 v = *(const floatx4*)(W2 + (size_t)t * 4);
        v *= (-1.0f / LOG2E);
        *(floatx4*)(w2q + (size_t)t * 4) = v;
    } else if (bid < 1280) {
        int t = (bid - 1152) * 256 + tid;    // zero out[] (atomics accumulate)
        floatx4 z = {};
        *(floatx4*)(out + (size_t)t * 4) = z;
    } else if (tid < 64) {
        float s = 0.0f;
        for (int i = 0; i < 64; ++i) s += B2[i * 64 + tid];
        b2sum[tid] = s;
    }
}

// silu with 4-way batched reciprocal over one packed HALF (float2 lanes = 2
// r-groups). All non-trans math as v_pk_* (dual-issue packed f32):
//   sum_i u_i/d_i, d_i = 1+2^(a_i), u_i = a_i*w_i  (weights pre-scaled)
// 18 pk + 8 exp2 + 2 rcp per call (two calls per iteration).
__device__ __forceinline__ void silu8(
        floatx2 A0, floatx2 A1, floatx2 A2, floatx2 A3,
        floatx2 W0, floatx2 W1, floatx2 W2, floatx2 W3,
        floatx2 one2, floatx2& phi) {
    floatx2 E0 = {__builtin_amdgcn_exp2f(A0[0]), __builtin_amdgcn_exp2f(A0[1])};
    floatx2 E1 = {__builtin_amdgcn_exp2f(A1[0]), __builtin_amdgcn_exp2f(A1[1])};
    floatx2 E2 = {__builtin_amdgcn_exp2f(A2[0]), __builtin_amdgcn_exp2f(A2[1])};
    floatx2 E3 = {__builtin_amdgcn_exp2f(A3[0]), __builtin_amdgcn_exp2f(A3[1])};
    floatx2 D0 = pk_add(E0, one2), D1 = pk_add(E1, one2);
    floatx2 D2 = pk_add(E2, one2), D3 = pk_add(E3, one2);
    floatx2 U0 = pk_mul(A0, W0), U1 = pk_mul(A1, W1);
    floatx2 U2 = pk_mul(A2, W2), U3 = pk_mul(A3, W3);
    floatx2 N01 = pk_fma(U0, D1, pk_mul(U1, D0));
    floatx2 N23 = pk_fma(U2, D3, pk_mul(U3, D2));
    floatx2 P01 = pk_mul(D0, D1), P23 = pk_mul(D2, D3);
    floatx2 N   = pk_fma(N01, P23, pk_mul(N23, P01));
    floatx2 DD  = pk_mul(P01, P23);
    floatx2 R = {__builtin_amdgcn_rcpf(DD[0]), __builtin_amdgcn_rcpf(DD[1])};
    phi = pk_fma(N, R, phi);
}

// ---------------------------------------------------------------------------
// main: grid = 4 ig x 32 og x 64 btp = 8192 blocks, block = 128 (2 waves);
// wave w -> o = og*2+w, i in [ig*16, ig*16+16). Per i: ONE mfma_32x32x8
// (K=8 exact) -> C[h(32) x b(32)]. w2 slice staged in LDS (broadcast
// ds_read_b128). silu via packed-f32 batched-rcp tree (silu8 x2).
// MFMA runs ONE ITERATION AHEAD of silu (C double-buffer): mfma(ii+1)
// issues before silu(ii) consumes Ccur, so MFMA latency is never exposed.
// Results atomically added to out, carrying 1/NIG of b2sum each.
// ---------------------------------------------------------------------------
__global__ __launch_bounds__(128, 6) void main_kernel(
        const f16* __restrict__ w1img, const f16* __restrict__ fimg,
        const float* __restrict__ w2q, const float* __restrict__ b2sum,
        float* __restrict__ out) {
    const int tid  = threadIdx.x;
    const int lane = tid & 63;
    const int wv   = tid >> 6;
    const int btp  = blockIdx.x & 63;
    const int og   = (blockIdx.x >> 6) & 31;
    const int ig   = blockIdx.x >> 11;
    const int o    = __builtin_amdgcn_readfirstlane(og * 2 + wv);
    const int p    = lane >> 5;
    const size_t ibase = (size_t)ig * IGW;

    // stage w2 slice: [wave][ii][h]
    __shared__ float ws2[2][IGW + 1][32];
    {
        int idx = tid * 8;                         // 8 floats per thread
        int wv_ = idx >> 9, ii_ = (idx >> 5) & 15, h_ = idx & 31;
        const float* src = w2q + (ibase + ii_) * 2048
                         + (size_t)(og * 2 + wv_) * 32 + h_;
        *(floatx4*)&ws2[wv_][ii_][h_]     = *(const floatx4*)src;
        *(floatx4*)&ws2[wv_][ii_][h_ + 4] = *(const floatx4*)(src + 4);
    }
    __syncthreads();

    const f16* ap = w1img + ibase * 16384 + ((size_t)o   * 64 + lane) * 4;
    const f16* bp = fimg  + ibase * 16384 + ((size_t)btp * 64 + lane) * 4;

    const floatx16 zeroC = {};
    const floatx2  one2  = {1.0f, 1.0f};
    floatx2 phiL = {}, phiH = {};

    // prologue: frag(0) -> Ccur; frag(1) staged in a_n/b_n
    f16x4 a0v = *(const f16x4*)ap;
    f16x4 b0v = *(const f16x4*)bp;
    f16x4 a_n = *(const f16x4*)(ap + 16384);
    f16x4 b_n = *(const f16x4*)(bp + 16384);
    floatx16 Ccur = __builtin_amdgcn_mfma_f32_32x32x8f16(a0v, b0v, zeroC, 0, 0, 0);

#pragma unroll 1
    for (int ii = 0; ii < IGW; ++ii) {
        // issue next MFMA before consuming Ccur (garbage at ii=15 — unused)
        floatx16 Cn = __builtin_amdgcn_mfma_f32_32x32x8f16(a_n, b_n, zeroC, 0, 0, 0);
        // prefetch frag(ii+2); tail overruns into adjacent ws regions —
        // loaded but never consumed, always in-bounds of the workspace
        const size_t i2 = (size_t)(ii + 2);
        a_n = *(const f16x4*)(ap + i2 * 16384);
        b_n = *(const f16x4*)(bp + i2 * 16384);

        const float* wrow = &ws2[wv][ii][p * 4];
        const floatx4 W0 = *(const floatx4*)(wrow);
        const floatx4 W1v = *(const floatx4*)(wrow + 8);
        const floatx4 W2v = *(const floatx4*)(wrow + 16);
        const floatx4 W3v = *(const floatx4*)(wrow + 24);

        // lo half: r = 0,1 ; hi half: r = 2,3
        silu8((floatx2){Ccur[0],  Ccur[1]},  (floatx2){Ccur[4],  Ccur[5]},
              (floatx2){Ccur[8],  Ccur[9]},  (floatx2){Ccur[12], Ccur[13]},
              (floatx2){W0[0], W0[1]}, (floatx2){W1v[0], W1v[1]},
              (floatx2){W2v[0], W2v[1]}, (floatx2){W3v[0], W3v[1]},
              one2, phiL);
        silu8((floatx2){Ccur[2],  Ccur[3]},  (floatx2){Ccur[6],  Ccur[7]},
              (floatx2){Ccur[10], Ccur[11]}, (floatx2){Ccur[14], Ccur[15]},
              (floatx2){W0[2], W0[3]}, (floatx2){W1v[2], W1v[3]},
              (floatx2){W2v[2], W2v[3]}, (floatx2){W3v[2], W3v[3]},
              one2, phiH);

        Ccur = Cn;
    }

    float phi = (phiL[0] + phiL[1]) + (phiH[0] + phiH[1]);
    // combine the two row-halves (lane and lane^32 share the same column)
    phi += __shfl_xor(phi, 32, 64);

    if (lane < 32) {
        float v = phi + 0.25f * b2sum[o];   // 1/NIG of bias per contribution
        unsafeAtomicAdd(out + (size_t)(btp * 32 + lane) * 64 + o, v);
    }
}

extern "C" void kernel_launch(void* const* d_in, const int* in_sizes, int n_in,
                              void* d_out, int out_size, void* d_ws, size_t ws_size,
                              hipStream_t stream) {
    const float* x  = (const float*)d_in[0];
    const float* W1 = (const float*)d_in[1];
    const float* W2 = (const float*)d_in[2];
    const float* B1 = (const float*)d_in[3];
    const float* B2 = (const float*)d_in[4];
    float* out = (float*)d_out;

    // ws: w1img (2MB) | fimg (2MB) | w2q (512KB) | b2sum | (overrun pad lives
    // in the contiguity of these regions; prefetch spills land in-bounds)
    f16*   w1img = (f16*)d_ws;
    f16*   fimg  = w1img + W1IMG_ELEMS;
    float* w2q   = (float*)(fimg + FIMG_ELEMS);
    float* b2sum = w2q + W2Q_ELEMS;

    prep_kernel<<<1281, 256, 0, stream>>>(W1, B1, W2, B2, x, w1img, fimg, w2q, b2sum, out);
    main_kernel<<<NIG * 32 * 64, 128, 0, stream>>>(w1img, fimg, w2q, b2sum, out);
}